// Round 13
// baseline (367.005 us; speedup 1.0000x reference)
//
#include <hip/hip_runtime.h>
#include <math.h>

#define B_ 16384
#define R_ 512
#define V_ 1000
#define F_ 300
#define FP_ 320           // F padded to multiple of 32
#define L_ 512
#define H_ 512
#define LEAK_ 0.2f
#define TEMP_ 0.07f
#define DISK_ 15

#define NCSL_BLK (B_ / 4)      // 4096
#define NKL_BLK  1024          // fused mu|ls gemm grid 8x128
#define NREC_BLK (3 * 128)     // 384 (recon 128-wide col tiles: 3 x 128)

#define NT_ 11
#define FRONT_TOPK_BLK 3277        // ceil(16384/5)
#define FRONT_GATHER_BLK R_        // 512
#define FRONT_TRANS_BLK (16 * 16 * NT_)  // 2816

typedef short short8 __attribute__((ext_vector_type(8)));
typedef float float4v __attribute__((ext_vector_type(4)));

__device__ __forceinline__ float waveReduceSum(float v) {
#pragma unroll
    for (int off = 32; off; off >>= 1) v += __shfl_xor(v, off);
    return v;
}

__device__ __forceinline__ short f2bf(float f) {
    unsigned u = __float_as_uint(f);
    unsigned r = (u + 0x7FFFu + ((u >> 16) & 1u)) >> 16;
    return (short)r;
}

// async global->LDS, 16B per lane; LDS dest = wave-uniform base + lane*16
__device__ __forceinline__ void gld16(const short* g, short* l) {
    __builtin_amdgcn_global_load_lds(
        (const __attribute__((address_space(1))) void*)g,
        (__attribute__((address_space(3))) void*)l, 16, 0, 0);
}

// ---------------------------------------------------------------------------
// producer->consumer XCD affinity (r12, confirmed: total 375->362, consumer
// GEMMs dropped out of top-5). Global rule: XCD k (= raw linear blockIdx % 8)
// owns B-rows [2048k, 2048(k+1)), i.e. 128-row tiles by in [16k, 16k+16).
// ---------------------------------------------------------------------------
__device__ __forceinline__ void xcd_swizzle(int& bx, int& by) {
    int gx = gridDim.x;
    int nwg = gx * gridDim.y;
    int wg = blockIdx.x + gx * blockIdx.y;
    int cpx = nwg >> 3;
    int swz = (wg & 7) * cpx + (wg >> 3);
    bx = swz % gx;
    by = swz / gx;
}

// ---------------------------------------------------------------------------
// merged front-end: topk (jobs 0..3276) | gather (next 512) | transpose (2816)
// ---------------------------------------------------------------------------
struct TransArgs {
    const float* W[NT_];
    short* Wt[NT_];
    int row_off[NT_];
    int K[NT_];
    int Kpad[NT_];
    int N[NT_];
    int Npad[NT_];
    int ilv[NT_];
};

__device__ void topk_body(int b, int lane, const float* __restrict__ logits,
                          int* __restrict__ top0, int* __restrict__ top1,
                          int* __restrict__ dis) {
    const float* lp = logits + (size_t)b * R_;
    float4 va = *(const float4*)&lp[lane * 8];
    float4 vb = *(const float4*)&lp[lane * 8 + 4];
    float v[8] = {va.x, va.y, va.z, va.w, vb.x, vb.y, vb.z, vb.w};
    unsigned u[8];
#pragma unroll
    for (int i = 0; i < 8; ++i) {
        int f = __float_as_int(v[i]);
        u[i] = (unsigned)f ^ ((unsigned)(f >> 31) | 0x80000000u);
    }
    unsigned long long t1 = 0ull, t2 = 0ull;
#pragma unroll
    for (int i = 0; i < 8; ++i) {
        unsigned long long k =
            ((unsigned long long)u[i] << 9) | (unsigned)(511 - (lane * 8 + i));
        if (k > t1) { t2 = t1; t1 = k; }
        else if (k > t2) t2 = k;
    }
#pragma unroll
    for (int off = 32; off; off >>= 1) {
        unsigned long long o1 = __shfl_xor(t1, off);
        unsigned long long o2 = __shfl_xor(t2, off);
        unsigned long long hi = t1 > o1 ? t1 : o1;
        unsigned long long lo = t1 > o1 ? o1 : t1;
        unsigned long long m2 = t2 > o2 ? t2 : o2;
        t1 = hi;
        t2 = lo > m2 ? lo : m2;
    }
    int i0 = 511 - (int)(t1 & 511u);
    int i1 = 511 - (int)(t2 & 511u);

    unsigned k32[8];
#pragma unroll
    for (int i = 0; i < 8; ++i) {
        int idx = lane * 8 + i;
        k32[i] = (u[i] & 0xFFFFFE00u) | (unsigned)idx;
        if (idx == i0 || idx == i1) k32[i] = 0xFFFFFFFFu;
    }
    unsigned lmin = k32[0];
#pragma unroll
    for (int i = 1; i < 8; ++i) lmin = min(lmin, k32[i]);
    int dloc[DISK_];
#pragma unroll
    for (int t = 0; t < DISK_; ++t) {
        unsigned w = lmin;
#pragma unroll
        for (int off = 32; off; off >>= 1) w = min(w, __shfl_xor(w, off));
        int idx = (int)(w & 0x1FFu);
        dloc[t] = idx;
        if ((idx >> 3) == lane) {
            k32[idx & 7] = 0xFFFFFFFFu;
            lmin = k32[0];
#pragma unroll
            for (int i = 1; i < 8; ++i) lmin = min(lmin, k32[i]);
        }
    }
    if (lane == 0) {
        top0[b] = i0; top1[b] = i1;
#pragma unroll
        for (int t = 0; t < DISK_; ++t) dis[b * DISK_ + t] = dloc[t];
    }
}

__global__ __launch_bounds__(320) void front_kernel(
    const float* __restrict__ logits, int* __restrict__ top0,
    int* __restrict__ top1, int* __restrict__ dis,
    const int* __restrict__ rels32, const float* __restrict__ rel_dict,
    float* __restrict__ d_table, short* __restrict__ dt, TransArgs ta) {
    __shared__ float tile[32][33];
    __shared__ int s_i64;
    int blk = blockIdx.x;
    int tid = threadIdx.x;

    if (blk < FRONT_TOPK_BLK) {
        int b = blk * 5 + (tid >> 6);
        if (b < B_) topk_body(b, tid & 63, logits, top0, top1, dis);
        return;
    }
    blk -= FRONT_TOPK_BLK;
    if (blk < FRONT_GATHER_BLK) {
        int r = blk;
        if (tid == 0) s_i64 = 1;
        __syncthreads();
        if (rels32[2 * tid + 1] != 0) s_i64 = 0;
        __syncthreads();
        int key = s_i64 ? rels32[4 * r + 2] : rels32[2 * r + 1];
        if (tid < F_) {
            float v = rel_dict[(size_t)key * F_ + tid];
            d_table[(size_t)r * F_ + tid] = v;
            dt[(size_t)r * FP_ + tid] = f2bf(v);
        } else {
            dt[(size_t)r * FP_ + tid] = 0;
        }
        return;
    }
    blk -= FRONT_GATHER_BLK;
    {
        int z = blk >> 8;
        int kx = blk & 15, ny = (blk >> 4) & 15;
        const float* W = ta.W[z];
        short* Wt = ta.Wt[z];
        int row_off = ta.row_off[z];
        int K = ta.K[z], Kpad = ta.Kpad[z], N = ta.N[z], Npad = ta.Npad[z];
        int ilv = ta.ilv[z];
        int k0 = kx * 32, n0 = ny * 32;
        bool live = (k0 < Kpad) && (n0 < Npad);
        bool act = live && (tid < 256);
        int tx = tid & 31, ty = tid >> 5;
        if (act) {
#pragma unroll
            for (int i = 0; i < 4; ++i) {
                int k = k0 + i * 8 + ty, n = n0 + tx;
                tile[i * 8 + ty][tx] =
                    (k < K && n < N) ? W[(size_t)(row_off + k) * N + n] : 0.f;
            }
        }
        __syncthreads();
        if (act) {
#pragma unroll
            for (int i = 0; i < 4; ++i) {
                int n = n0 + i * 8 + ty, k = k0 + tx;
                if (n < Npad && k < Kpad) {
                    int orow = (ilv >= 0) ? (ilv + 128 * (n >> 6) + (n & 63)) : n;
                    Wt[(size_t)orow * Kpad + k] = f2bf(tile[tx][i * 8 + ty]);
                }
            }
        }
    }
}

// ---------------------------------------------------------------------------
// h1 = leaky(Pcat[top0,0:512] + Pcat[top1,512:1024] + b1)  -> bf16
// XCD-affine block remap (r12).
// ---------------------------------------------------------------------------
__global__ __launch_bounds__(256) void h1_kernel(
    const float* __restrict__ Pcat, const float* __restrict__ b1,
    const int* __restrict__ top0, const int* __restrict__ top1,
    short* __restrict__ h1b) {
    int blk = (blockIdx.x & 7) * 4096 + (blockIdx.x >> 3);  // 32768 blocks
    int idx = blk * 256 + threadIdx.x;
    int b = idx >> 9, j = idx & 511;
    float v = Pcat[(size_t)top0[b] * 2048 + j] + Pcat[(size_t)top1[b] * 2048 + 512 + j] + b1[j];
    h1b[idx] = f2bf(v > 0.f ? v : LEAK_ * v);
}

// ---------------------------------------------------------------------------
// core == ROUND 7 core (best measured config).
// 128x128, K=512, BK=64, 4 waves, double-buffered, COUNTED vmcnt (T4).
// ---------------------------------------------------------------------------
__device__ __forceinline__ const short8* frag_at(const short* buf, int row, int cb) {
    return (const short8*)&buf[row * 64 + ((cb ^ (row & 7)) * 8)];
}

__device__ __forceinline__ void gemm_core(
    const short* __restrict__ A, const short* __restrict__ Wt,
    int row0, int col0, int tid, short* As0, short* Bs0,
    short* As1, short* Bs1, float4v (&acc)[2][8]) {
    const int K = 512;
    int lane = tid & 63, wv = tid >> 6;
    int lm = lane & 15, q = lane >> 4;
    int rsub = lane >> 3;
    int kswz = ((lane & 7) ^ rsub) * 8;
    int ga = row0 + wv * 8 + rsub;
    int gb = col0 + wv * 8 + rsub;
#pragma unroll
    for (int i = 0; i < 2; ++i)
#pragma unroll
        for (int j = 0; j < 8; ++j) acc[i][j] = {0.f, 0.f, 0.f, 0.f};

    auto STAGE = [&](short* lA, short* lB, int k0) {
#pragma unroll
        for (int j = 0; j < 4; ++j) {
            gld16(&A[(size_t)(ga + 32 * j) * K + k0 + kswz],
                  lA + (wv * 8 + 32 * j) * 64);
            gld16(&Wt[(size_t)(gb + 32 * j) * K + k0 + kswz],
                  lB + (wv * 8 + 32 * j) * 64);
        }
    };

    STAGE(As0, Bs0, 0);
#pragma unroll
    for (int t = 0; t < 8; ++t) {
        short* cA = (t & 1) ? As1 : As0;
        short* cB = (t & 1) ? Bs1 : Bs0;
        short* nA = (t & 1) ? As0 : As1;
        short* nB = (t & 1) ? Bs0 : Bs1;
        if (t < 7) {
            STAGE(nA, nB, (t + 1) * 64);
            asm volatile("s_waitcnt vmcnt(8)" ::: "memory");
        } else {
            asm volatile("s_waitcnt vmcnt(0)" ::: "memory");
        }
        __builtin_amdgcn_s_barrier();
        __builtin_amdgcn_sched_barrier(0);
#pragma unroll
        for (int kk = 0; kk < 2; ++kk) {
            short8 af[2], bf[8];
#pragma unroll
            for (int mt = 0; mt < 2; ++mt)
                af[mt] = *frag_at(cA, wv * 32 + mt * 16 + lm, kk * 4 + q);
#pragma unroll
            for (int nt = 0; nt < 8; ++nt)
                bf[nt] = *frag_at(cB, nt * 16 + lm, kk * 4 + q);
#pragma unroll
            for (int mt = 0; mt < 2; ++mt)
#pragma unroll
                for (int nt = 0; nt < 8; ++nt)
                    acc[mt][nt] = __builtin_amdgcn_mfma_f32_16x16x32_bf16(
                        af[mt], bf[nt], acc[mt][nt], 0, 0, 0);
        }
        __builtin_amdgcn_s_barrier();
    }
}

// epilogues ----------------------------------------------------------------
template <int MODE>
__device__ __forceinline__ void epi_std(
    float4v (&acc)[2][8], int row0, int col0, int tid, void* C,
    const float* __restrict__ bias, const float* __restrict__ table,
    int tld, const int* __restrict__ rowsel) {
    int lane = tid & 63, wv = tid >> 6;
    int lm = lane & 15, q = lane >> 4;
#pragma unroll
    for (int mt = 0; mt < 2; ++mt)
#pragma unroll
        for (int r = 0; r < 4; ++r) {
            int grow = row0 + wv * 32 + mt * 16 + q * 4 + r;
            int trow = (MODE == 1) ? rowsel[grow] : 0;
#pragma unroll
            for (int nt = 0; nt < 8; ++nt) {
                int gcol = col0 + nt * 16 + lm;
                float v = acc[mt][nt][r] + bias[gcol];
                if (MODE == 1) {
                    v += table[(size_t)trow * tld + gcol];
                    v = v > 0.f ? v : LEAK_ * v;
                } else {
                    v = v > 0.f ? v : 0.f;
                }
                if (MODE == 4)
                    ((float*)C)[(size_t)grow * 512 + gcol] = v;
                else
                    ((short*)C)[(size_t)grow * 512 + gcol] = f2bf(v);
            }
        }
}

__device__ __forceinline__ void epi_recon(
    float4v (&acc)[2][8], int row0, int col0, int tid,
    const float* __restrict__ b4, const float* __restrict__ d_table,
    const int* __restrict__ top0, float* __restrict__ p_rec, int pidx,
    float* sred) {
    int lane = tid & 63, wv = tid >> 6;
    int lm = lane & 15, q = lane >> 4;
    float lsum = 0.f;
#pragma unroll
    for (int mt = 0; mt < 2; ++mt)
#pragma unroll
        for (int r = 0; r < 4; ++r) {
            int grow = row0 + wv * 32 + mt * 16 + q * 4 + r;
            int trow = top0[grow];
#pragma unroll
            for (int nt = 0; nt < 8; ++nt) {
                int gcol = col0 + nt * 16 + lm;
                if (gcol < F_) {
                    float v = tanhf(acc[mt][nt][r] + b4[gcol]);
                    float d = v - d_table[(size_t)trow * F_ + gcol];
                    lsum += d * d;
                }
            }
        }
    lsum = waveReduceSum(lsum);
    if (lane == 0) sred[wv] = lsum;
    __syncthreads();
    if (tid == 0) p_rec[pidx] = sred[0] + sred[1] + sred[2] + sred[3];
}

// ---------------------------------------------------------------------------
// mu|ls fused GEMM + reparam + KL partial. grid (8,128).
// ---------------------------------------------------------------------------
__global__ __launch_bounds__(256) void gemm_muls(
    const short* __restrict__ A, const short* __restrict__ Wt,
    short* __restrict__ Cz, short* __restrict__ Cz2,
    const float* __restrict__ bmu, const float* __restrict__ bls,
    const float* __restrict__ eps1, const float* __restrict__ eps2,
    float* __restrict__ p_kl) {
    __shared__ __align__(16) short As[2][128 * 64];
    __shared__ __align__(16) short Bs[2][128 * 64];
    __shared__ float sred[4];
    int tid = threadIdx.x;
    int bx, by;
    xcd_swizzle(bx, by);
    int row0 = by * 128, col0 = bx * 128;
    float4v acc[2][8];
    gemm_core(A, Wt, row0, col0, tid, As[0], Bs[0], As[1], Bs[1], acc);

    int lane = tid & 63, wv = tid >> 6;
    int lm = lane & 15, q = lane >> 4;
    float kl = 0.f;
#pragma unroll
    for (int mt = 0; mt < 2; ++mt) {
#pragma unroll
        for (int r = 0; r < 4; ++r) {
            int grow = row0 + wv * 32 + mt * 16 + q * 4 + r;
#pragma unroll
            for (int jj = 0; jj < 4; ++jj) {
                int j = (col0 >> 1) + jj * 16 + lm;
                float m = acc[mt][jj][r] + bmu[j];
                float lsv = acc[mt][jj + 4][r] + bls[j];
                float s = __expf(lsv);
                size_t ix = (size_t)grow * 512 + j;
                Cz[ix]  = f2bf(m + eps1[ix] * s);
                Cz2[ix] = f2bf(m + eps2[ix] * s);
                kl += -0.5f * (1.f + 2.f * lsv - m * m - s * s);
            }
        }
    }
    kl = waveReduceSum(kl);
    if (lane == 0) sred[wv] = kl;
    __syncthreads();
    if (tid == 0)
        p_kl[bx + gridDim.x * by] = sred[0] + sred[1] + sred[2] + sred[3];
}

// ---------------------------------------------------------------------------
// dual launch 1: {h3 (512) | t (512) | ipost (16)}; XCD-affine decode (r12)
// ---------------------------------------------------------------------------
__global__ __launch_bounds__(256) void dual12_kernel(
    const short* __restrict__ zA, const short* __restrict__ Wt3,
    short* __restrict__ h3out, const float* __restrict__ b3,
    const float* __restrict__ Ptab, const int* __restrict__ top1,
    const short* __restrict__ zpA, const short* __restrict__ Wtz1,
    short* __restrict__ tout, const float* __restrict__ zb1,
    const short* __restrict__ ipreA, const short* __restrict__ Wti2,
    float* __restrict__ ipostC, const float* __restrict__ ib2,
    int jobSel) {
    __shared__ __align__(16) short As[2][128 * 64];
    __shared__ __align__(16) short Bs[2][128 * 64];
    int tid = threadIdx.x;
    int k = blockIdx.x & 7, m = blockIdx.x >> 3;
    int job, bx, by;
    if (jobSel >= 0) {
        job = jobSel;
        if (job == 2) { int idx = k * 2 + m; bx = idx & 3; by = idx >> 2; }
        else { bx = m & 3; by = 16 * k + (m >> 2); }
    } else {
        if (m < 64)       { job = 0; bx = m & 3; by = 16 * k + (m >> 2); }
        else if (m < 128) { int mm = m - 64; job = 1; bx = mm & 3; by = 16 * k + (mm >> 2); }
        else              { int mm = m - 128; job = 2; int idx = k * 2 + mm; bx = idx & 3; by = idx >> 2; }
    }
    int row0 = by * 128, col0 = bx * 128;
    float4v acc[2][8];
    if (job == 0) {
        gemm_core(zA, Wt3, row0, col0, tid, As[0], Bs[0], As[1], Bs[1], acc);
        epi_std<1>(acc, row0, col0, tid, h3out, b3, Ptab, 2048, top1);
    } else if (job == 1) {
        gemm_core(zpA, Wtz1, row0, col0, tid, As[0], Bs[0], As[1], Bs[1], acc);
        epi_std<2>(acc, row0, col0, tid, tout, zb1, nullptr, 0, nullptr);
    } else {
        gemm_core(ipreA, Wti2, row0, col0, tid, As[0], Bs[0], As[1], Bs[1], acc);
        epi_std<4>(acc, row0, col0, tid, ipostC, ib2, nullptr, 0, nullptr);
    }
}

// ---------------------------------------------------------------------------
// dual launch 2: {z_p (512) | recon (384)}; XCD-affine decode (r12)
// ---------------------------------------------------------------------------
__global__ __launch_bounds__(256) void dual34_kernel(
    const short* __restrict__ tA, const short* __restrict__ Wtz2,
    float* __restrict__ zpout, const float* __restrict__ zb2,
    const short* __restrict__ h3A, const short* __restrict__ Wt4,
    const float* __restrict__ b4, const float* __restrict__ d_table,
    const int* __restrict__ top0, float* __restrict__ p_rec, int jobSel) {
    __shared__ __align__(16) short As[2][128 * 64];
    __shared__ __align__(16) short Bs[2][128 * 64];
    __shared__ float sred[4];
    int tid = threadIdx.x;
    int k = blockIdx.x & 7, m = blockIdx.x >> 3;
    int job, bx, by;
    if (jobSel >= 0) {
        job = jobSel;
        if (job == 0) { bx = m & 3; by = 16 * k + (m >> 2); }
        else          { bx = m % 3; by = 16 * k + m / 3; }
    } else {
        if (m < 64) { job = 0; bx = m & 3; by = 16 * k + (m >> 2); }
        else        { int mm = m - 64; job = 1; bx = mm % 3; by = 16 * k + mm / 3; }
    }
    float4v acc[2][8];
    if (job == 0) {
        int row0 = by * 128, col0 = bx * 128;
        gemm_core(tA, Wtz2, row0, col0, tid, As[0], Bs[0], As[1], Bs[1], acc);
        epi_std<4>(acc, row0, col0, tid, zpout, zb2, nullptr, 0, nullptr);
    } else {
        int row0 = by * 128, col0 = bx * 128;
        gemm_core(h3A, Wt4, row0, col0, tid, As[0], Bs[0], As[1], Bs[1], acc);
        epi_recon(acc, row0, col0, tid, b4, d_table, top0, p_rec,
                  bx + 3 * by, sred);
    }
}

// ---------------------------------------------------------------------------
// ROUND 13: Pcat GEMM retiled 128x64 -> 64x64, grid (32,8) = 256 blocks
// (was 128 -> half the CUs idle on a latency-bound loop). 4 waves, each
// owns one 16-row M-frag x 64 cols. Same reg-staged dbuf loop + EPI6
// fused-ipre epilogue. LDS ~20KB.
// ---------------------------------------------------------------------------
template <int KK>
__global__ __launch_bounds__(256) void gemm_mfma64(
    const short* __restrict__ A, const short* __restrict__ Wt,
    float* __restrict__ C, int ldc, const float* __restrict__ ib1,
    short* __restrict__ ipre_out) {
    __shared__ __align__(16) short Asl[2][64][40];
    __shared__ __align__(16) short Bsl[2][64][40];
    int tid = threadIdx.x;
    int lane = tid & 63, wv = tid >> 6;
    int lm = lane & 15, q = lane >> 4;
    int bx, by;
    xcd_swizzle(bx, by);
    int row0 = by * 64;
    int col0 = bx * 64;

    float4v acc[4];
#pragma unroll
    for (int j = 0; j < 4; ++j) acc[j] = {0.f, 0.f, 0.f, 0.f};

    uint4 aReg, bReg;
    int ar = tid >> 2, ak = (tid & 3) * 8;   // 64 rows x 32 shorts: 1 uint4/thread

    auto loadG = [&](int k0) {
        aReg = *(const uint4*)&A[(size_t)(row0 + ar) * KK + k0 + ak];
        bReg = *(const uint4*)&Wt[(size_t)(col0 + ar) * KK + k0 + ak];
    };
    auto storeL = [&](int p) {
        *(uint4*)&Asl[p][ar][ak] = aReg;
        *(uint4*)&Bsl[p][ar][ak] = bReg;
    };

    int p = 0;
    loadG(0);
    storeL(0);
    for (int k0 = 0; k0 < KK; k0 += 32) {
        __syncthreads();
        bool more = (k0 + 32) < KK;
        if (more) loadG(k0 + 32);
        short8 af, bfr[4];
        af = *(const short8*)&Asl[p][wv * 16 + lm][q * 8];
#pragma unroll
        for (int nt = 0; nt < 4; ++nt)
            bfr[nt] = *(const short8*)&Bsl[p][nt * 16 + lm][q * 8];
#pragma unroll
        for (int nt = 0; nt < 4; ++nt)
            acc[nt] = __builtin_amdgcn_mfma_f32_16x16x32_bf16(
                af, bfr[nt], acc[nt], 0, 0, 0);
        if (more) { p ^= 1; storeL(p); }
    }

#pragma unroll
    for (int r = 0; r < 4; ++r) {
        int grow = row0 + wv * 16 + q * 4 + r;
#pragma unroll
        for (int nt = 0; nt < 4; ++nt) {
            int gcol = col0 + nt * 16 + lm;
            float v = acc[nt][r];
            C[(size_t)grow * ldc + gcol] = v;
            if (gcol >= 1536) {
                int j = gcol - 1536;
                float w = v + ib1[j];
                ipre_out[(size_t)grow * 512 + j] = f2bf(w > 0.f ? w : 0.f);
            }
        }
    }
}

// ---------------------------------------------------------------------------
// contrastive loss: one wave per row; XCD-affine block remap (r12)
// ---------------------------------------------------------------------------
__global__ __launch_bounds__(256) void csl_kernel(
    const float* __restrict__ zp, const float* __restrict__ ipost,
    const int* __restrict__ top0, const int* __restrict__ dis,
    float* __restrict__ partial_csl) {
    __shared__ float sred[4];
    int blk = (blockIdx.x & 7) * 512 + (blockIdx.x >> 3);   // 4096 blocks
    int w = threadIdx.x >> 6, lane = threadIdx.x & 63;
    int b = blk * 4 + w;
    const float* zr = zp + (size_t)b * 512;
    float z[8];
#pragma unroll
    for (int i = 0; i < 8; ++i) z[i] = zr[i * 64 + lane];
    int cand[16];
    cand[0] = top0[b];
#pragma unroll
    for (int n = 0; n < DISK_; ++n) cand[n + 1] = dis[b * DISK_ + n];
    float s[16];
#pragma unroll
    for (int c = 0; c < 16; ++c) {
        const float* ip = ipost + (size_t)cand[c] * 512;
        float a = 0.f;
#pragma unroll
        for (int i = 0; i < 8; ++i) a += z[i] * ip[i * 64 + lane];
        s[c] = a;
    }
#pragma unroll
    for (int off = 32; off; off >>= 1) {
        float o[16];
#pragma unroll
        for (int c = 0; c < 16; ++c) o[c] = __shfl_xor(s[c], off);
#pragma unroll
        for (int c = 0; c < 16; ++c) s[c] += o[c];
    }
    if (lane == 0) {
        float m = s[0];
#pragma unroll
        for (int c = 1; c < 16; ++c) m = fmaxf(m, s[c]);
        float se = 0.f;
#pragma unroll
        for (int c = 0; c < 16; ++c) se += __expf((s[c] - m) / TEMP_);
        sred[w] = -((s[0] - m) / TEMP_ - __logf(se));
    }
    __syncthreads();
    if (threadIdx.x == 0)
        partial_csl[blk] = sred[0] + sred[1] + sred[2] + sred[3];
}

// ---------------------------------------------------------------------------
// finalize: out[0] = kl + recon; out[1] = csl; out[2..513] = 0 (z_rel row 0)
// ---------------------------------------------------------------------------
__global__ __launch_bounds__(256) void finalize_kernel(
    const float* __restrict__ pkl, const float* __restrict__ prec,
    const float* __restrict__ pcsl, float* __restrict__ out) {
    __shared__ float red[4][2];
    int tid = threadIdx.x;
    out[2 + tid] = 0.f;
    out[2 + 256 + tid] = 0.f;
    float a0 = 0.f, a1 = 0.f;
    for (int i = tid; i < NKL_BLK; i += 256) a0 += pkl[i];
    for (int i = tid; i < NREC_BLK; i += 256) a0 += prec[i];
    for (int i = tid; i < NCSL_BLK; i += 256) a1 += pcsl[i];
    a0 = waveReduceSum(a0);
    a1 = waveReduceSum(a1);
    int lane = tid & 63, w = tid >> 6;
    if (lane == 0) { red[w][0] = a0; red[w][1] = a1; }
    __syncthreads();
    if (tid == 0) out[0] = red[0][0] + red[1][0] + red[2][0] + red[3][0];
    if (tid == 1) out[1] = red[0][1] + red[1][1] + red[2][1] + red[3][1];
}

// ---------------------------------------------------------------------------
extern "C" void kernel_launch(void* const* d_in, const int* in_sizes, int n_in,
                              void* d_out, int out_size, void* d_ws, size_t ws_size,
                              hipStream_t stream) {
    const float* logits  = (const float*)d_in[0];
    const int*   rels    = (const int*)d_in[1];
    const float* rel_dict= (const float*)d_in[2];
    const float* eps1    = (const float*)d_in[3];
    const float* eps2    = (const float*)d_in[4];
    const float* W1  = (const float*)d_in[5];
    const float* b1  = (const float*)d_in[6];
    const float* Wmu = (const float*)d_in[7];
    const float* bmu = (const float*)d_in[8];
    const float* Wls = (const float*)d_in[9];
    const float* bls = (const float*)d_in[10];
    const float* W3  = (const float*)d_in[11];
    const float* b3  = (const float*)d_in[12];
    const float* W4  = (const float*)d_in[13];
    const float* b4  = (const float*)d_in[14];
    const float* iW1 = (const float*)d_in[15];
    const float* ib1 = (const float*)d_in[16];
    const float* iW2 = (const float*)d_in[17];
    const float* ib2 = (const float*)d_in[18];
    const float* zW1 = (const float*)d_in[19];
    const float* zb1 = (const float*)d_in[20];
    const float* zW2 = (const float*)d_in[21];
    const float* zb2 = (const float*)d_in[22];
    float* out = (float*)d_out;

    char* wsp = (char*)d_ws;
    size_t off = 0;
    auto alloc = [&](size_t bytes) { void* p = wsp + off; off += (bytes + 255) & ~(size_t)255; return p; };
    int*   top0    = (int*)alloc(B_ * 4);
    int*   top1    = (int*)alloc(B_ * 4);
    int*   dis     = (int*)alloc(B_ * DISK_ * 4);
    float* d_table = (float*)alloc((size_t)R_ * F_ * 4);
    short* dt      = (short*)alloc((size_t)R_ * FP_ * 2);
    short* Wcat_t  = (short*)alloc((size_t)2048 * FP_ * 2);
    float* Pcat    = (float*)alloc((size_t)R_ * 2048 * 4);
    short* ipre    = (short*)alloc((size_t)R_ * H_ * 2);
    float* ipost   = (float*)alloc((size_t)R_ * H_ * 4);
    short* Wt_muls = (short*)alloc((size_t)1024 * 512 * 2);
    short* Wt_3    = (short*)alloc((size_t)512 * 512 * 2);
    short* Wt_z1   = (short*)alloc((size_t)512 * 512 * 2);
    short* Wt_z2   = (short*)alloc((size_t)512 * 512 * 2);
    short* Wt_4    = (short*)alloc((size_t)384 * 512 * 2);  // padded to 384 rows
    short* Wt_i2   = (short*)alloc((size_t)512 * 512 * 2);
    short* bfA     = (short*)alloc((size_t)B_ * H_ * 2);   // h1 -> h3
    short* bfB     = (short*)alloc((size_t)B_ * H_ * 2);   // z
    short* bfC     = (short*)alloc((size_t)B_ * H_ * 2);   // z_
    float* p_csl   = (float*)alloc(NCSL_BLK * 4);
    float* p_kl    = (float*)alloc(NKL_BLK * 4);
    float* p_rec   = (float*)alloc(NREC_BLK * 4);
    // t buffer: only if workspace allows (enables the merged dual launches)
    size_t bfD_bytes = (size_t)B_ * H_ * 2;
    bool merged = (off + bfD_bytes + 256) <= ws_size;
    short* bfD = merged ? (short*)alloc(bfD_bytes) : bfB;

    TransArgs ta;
    auto set = [&](int i, const float* W, short* Wt, int ro, int K, int Kp, int N, int Np, int ilv) {
        ta.W[i] = W; ta.Wt[i] = Wt; ta.row_off[i] = ro; ta.K[i] = K;
        ta.Kpad[i] = Kp; ta.N[i] = N; ta.Npad[i] = Np; ta.ilv[i] = ilv;
    };
    set(0, Wmu, Wt_muls, 0, 512, 512, 512, 512, 0);    // rows 128c+[0,64)
    set(1, Wls, Wt_muls, 0, 512, 512, 512, 512, 64);   // rows 128c+[64,128)
    set(2, W3,  Wt_3,  0, 512, 512, 512, 512, -1);
    set(3, zW1, Wt_z1, 0, 512, 512, 512, 512, -1);
    set(4, zW2, Wt_z2, 0, 512, 512, 512, 512, -1);
    set(5, W4,  Wt_4,  0, 512, 512, 300, 384, -1);     // zero-padded cols 300..384
    set(6, W1,  Wcat_t,              0,  F_, FP_, 512, 512, -1);   // P1
    set(7, W1,  Wcat_t + 512 * FP_,  F_, F_, FP_, 512, 512, -1);   // P2
    set(8, W3,  Wcat_t + 1024 * FP_, L_, F_, FP_, 512, 512, -1);   // P3
    set(9, iW1, Wcat_t + 1536 * FP_, 0,  F_, FP_, 512, 512, -1);   // ipre
    set(10, iW2, Wt_i2, 0, 512, 512, 512, 512, -1);

    // merged front-end: topk | gather | transpose (one dispatch)
    front_kernel<<<FRONT_TOPK_BLK + FRONT_GATHER_BLK + FRONT_TRANS_BLK,
                   320, 0, stream>>>(
        logits, top0, top1, dis, rels, rel_dict, d_table, dt, ta);

    // Pcat[512][2048] = dt @ Wcat, fused ipre epilogue (cols 1536+)
    // r13: 64x64 tiles, grid (32,8)=256 blocks (was 128 -> half CUs idle)
    gemm_mfma64<FP_><<<dim3(32, 8), 256, 0, stream>>>(
        dt, Wcat_t, Pcat, 2048, ib1, ipre);
    h1_kernel<<<B_ * H_ / 256, 256, 0, stream>>>(Pcat, b1, top0, top1, bfA);

    // fused mu|ls -> z (bfB), z_ (bfC), kl partials
    gemm_muls<<<dim3(8, 128), 256, 0, stream>>>(
        bfA, Wt_muls, bfB, bfC, bmu, bls, eps1, eps2, p_kl);

    if (merged) {
        dual12_kernel<<<1040, 256, 0, stream>>>(
            bfB, Wt_3, bfA, b3, Pcat + 1024, top1,
            bfC, Wt_z1, bfD, zb1,
            ipre, Wt_i2, ipost, ib2, -1);
        dual34_kernel<<<896, 256, 0, stream>>>(
            bfD, Wt_z2, out + 2 + L_, zb2,
            bfA, Wt_4, b4, d_table, top0, p_rec, -1);
    } else {
        dual12_kernel<<<512, 256, 0, stream>>>(
            bfB, Wt_3, bfA, b3, Pcat + 1024, top1,
            bfC, Wt_z1, bfD, zb1, ipre, Wt_i2, ipost, ib2, 0);
        dual12_kernel<<<512, 256, 0, stream>>>(
            bfB, Wt_3, bfA, b3, Pcat + 1024, top1,
            bfC, Wt_z1, bfD, zb1, ipre, Wt_i2, ipost, ib2, 1);
        dual12_kernel<<<16, 256, 0, stream>>>(
            bfB, Wt_3, bfA, b3, Pcat + 1024, top1,
            bfC, Wt_z1, bfD, zb1, ipre, Wt_i2, ipost, ib2, 2);
        dual34_kernel<<<512, 256, 0, stream>>>(
            bfD, Wt_z2, out + 2 + L_, zb2,
            bfA, Wt_4, b4, d_table, top0, p_rec, 0);
        dual34_kernel<<<384, 256, 0, stream>>>(
            bfD, Wt_z2, out + 2 + L_, zb2,
            bfA, Wt_4, b4, d_table, top0, p_rec, 1);
    }

    csl_kernel<<<NCSL_BLK, 256, 0, stream>>>(out + 2 + L_, ipost, top0, dis, p_csl);
    finalize_kernel<<<1, 256, 0, stream>>>(p_kl, p_rec, p_csl, out);
}

// Round 14
// 348.328 us; speedup vs baseline: 1.0536x; 1.0536x over previous
//
#include <hip/hip_runtime.h>
#include <math.h>

#define B_ 16384
#define R_ 512
#define V_ 1000
#define F_ 300
#define FP_ 320           // F padded to multiple of 32
#define L_ 512
#define H_ 512
#define LEAK_ 0.2f
#define TEMP_ 0.07f
#define DISK_ 15

#define NCSL_BLK (B_ / 4)      // 4096
#define NKL_BLK  1024          // fused mu|ls gemm grid 8x128
#define NREC_BLK (3 * 128)     // 384 (recon 128-wide col tiles: 3 x 128)

#define NT_ 11
#define FRONT_GATHER_BLK R_        // 512
#define FRONT_TRANS_BLK (16 * 16 * NT_)  // 2816
#define PCAT_BLK 256               // 64x64 tiles, grid 32x8 flattened
#define TOPK_BLK (B_ / 4)          // 4096 blocks x 4 rows

typedef short short8 __attribute__((ext_vector_type(8)));
typedef float float4v __attribute__((ext_vector_type(4)));

__device__ __forceinline__ float waveReduceSum(float v) {
#pragma unroll
    for (int off = 32; off; off >>= 1) v += __shfl_xor(v, off);
    return v;
}

__device__ __forceinline__ short f2bf(float f) {
    unsigned u = __float_as_uint(f);
    unsigned r = (u + 0x7FFFu + ((u >> 16) & 1u)) >> 16;
    return (short)r;
}

// async global->LDS, 16B per lane; LDS dest = wave-uniform base + lane*16
__device__ __forceinline__ void gld16(const short* g, short* l) {
    __builtin_amdgcn_global_load_lds(
        (const __attribute__((address_space(1))) void*)g,
        (__attribute__((address_space(3))) void*)l, 16, 0, 0);
}

// ---------------------------------------------------------------------------
// producer->consumer XCD affinity (r12, confirmed). Global rule: XCD k
// (= raw linear blockIdx % 8) owns B-rows [2048k, 2048(k+1)).
// ---------------------------------------------------------------------------
__device__ __forceinline__ void xcd_swizzle(int& bx, int& by) {
    int gx = gridDim.x;
    int nwg = gx * gridDim.y;
    int wg = blockIdx.x + gx * blockIdx.y;
    int cpx = nwg >> 3;
    int swz = (wg & 7) * cpx + (wg >> 3);
    bx = swz % gx;
    by = swz / gx;
}

// ---------------------------------------------------------------------------
// front-end (r14: topk moved out to overlap with Pcat GEMM):
//   gather (blocks 0..511) | transpose (512..3327)
// ---------------------------------------------------------------------------
struct TransArgs {
    const float* W[NT_];
    short* Wt[NT_];
    int row_off[NT_];
    int K[NT_];
    int Kpad[NT_];
    int N[NT_];
    int Npad[NT_];
    int ilv[NT_];
};

__device__ void topk_body(int b, int lane, const float* __restrict__ logits,
                          int* __restrict__ top0, int* __restrict__ top1,
                          int* __restrict__ dis) {
    const float* lp = logits + (size_t)b * R_;
    float4 va = *(const float4*)&lp[lane * 8];
    float4 vb = *(const float4*)&lp[lane * 8 + 4];
    float v[8] = {va.x, va.y, va.z, va.w, vb.x, vb.y, vb.z, vb.w};
    unsigned u[8];
#pragma unroll
    for (int i = 0; i < 8; ++i) {
        int f = __float_as_int(v[i]);
        u[i] = (unsigned)f ^ ((unsigned)(f >> 31) | 0x80000000u);
    }
    unsigned long long t1 = 0ull, t2 = 0ull;
#pragma unroll
    for (int i = 0; i < 8; ++i) {
        unsigned long long k =
            ((unsigned long long)u[i] << 9) | (unsigned)(511 - (lane * 8 + i));
        if (k > t1) { t2 = t1; t1 = k; }
        else if (k > t2) t2 = k;
    }
#pragma unroll
    for (int off = 32; off; off >>= 1) {
        unsigned long long o1 = __shfl_xor(t1, off);
        unsigned long long o2 = __shfl_xor(t2, off);
        unsigned long long hi = t1 > o1 ? t1 : o1;
        unsigned long long lo = t1 > o1 ? o1 : t1;
        unsigned long long m2 = t2 > o2 ? t2 : o2;
        t1 = hi;
        t2 = lo > m2 ? lo : m2;
    }
    int i0 = 511 - (int)(t1 & 511u);
    int i1 = 511 - (int)(t2 & 511u);

    unsigned k32[8];
#pragma unroll
    for (int i = 0; i < 8; ++i) {
        int idx = lane * 8 + i;
        k32[i] = (u[i] & 0xFFFFFE00u) | (unsigned)idx;
        if (idx == i0 || idx == i1) k32[i] = 0xFFFFFFFFu;
    }
    unsigned lmin = k32[0];
#pragma unroll
    for (int i = 1; i < 8; ++i) lmin = min(lmin, k32[i]);
    int dloc[DISK_];
#pragma unroll
    for (int t = 0; t < DISK_; ++t) {
        unsigned w = lmin;
#pragma unroll
        for (int off = 32; off; off >>= 1) w = min(w, __shfl_xor(w, off));
        int idx = (int)(w & 0x1FFu);
        dloc[t] = idx;
        if ((idx >> 3) == lane) {
            k32[idx & 7] = 0xFFFFFFFFu;
            lmin = k32[0];
#pragma unroll
            for (int i = 1; i < 8; ++i) lmin = min(lmin, k32[i]);
        }
    }
    if (lane == 0) {
        top0[b] = i0; top1[b] = i1;
#pragma unroll
        for (int t = 0; t < DISK_; ++t) dis[b * DISK_ + t] = dloc[t];
    }
}

__global__ __launch_bounds__(320) void front_kernel(
    const int* __restrict__ rels32, const float* __restrict__ rel_dict,
    float* __restrict__ d_table, short* __restrict__ dt, TransArgs ta) {
    __shared__ float tile[32][33];
    __shared__ int s_i64;
    int blk = blockIdx.x;
    int tid = threadIdx.x;

    if (blk < FRONT_GATHER_BLK) {
        int r = blk;
        if (tid == 0) s_i64 = 1;
        __syncthreads();
        if (rels32[2 * tid + 1] != 0) s_i64 = 0;
        __syncthreads();
        int key = s_i64 ? rels32[4 * r + 2] : rels32[2 * r + 1];
        if (tid < F_) {
            float v = rel_dict[(size_t)key * F_ + tid];
            d_table[(size_t)r * F_ + tid] = v;
            dt[(size_t)r * FP_ + tid] = f2bf(v);
        } else {
            dt[(size_t)r * FP_ + tid] = 0;
        }
        return;
    }
    blk -= FRONT_GATHER_BLK;
    {
        int z = blk >> 8;
        int kx = blk & 15, ny = (blk >> 4) & 15;
        const float* W = ta.W[z];
        short* Wt = ta.Wt[z];
        int row_off = ta.row_off[z];
        int K = ta.K[z], Kpad = ta.Kpad[z], N = ta.N[z], Npad = ta.Npad[z];
        int ilv = ta.ilv[z];
        int k0 = kx * 32, n0 = ny * 32;
        bool live = (k0 < Kpad) && (n0 < Npad);
        bool act = live && (tid < 256);
        int tx = tid & 31, ty = tid >> 5;
        if (act) {
#pragma unroll
            for (int i = 0; i < 4; ++i) {
                int k = k0 + i * 8 + ty, n = n0 + tx;
                tile[i * 8 + ty][tx] =
                    (k < K && n < N) ? W[(size_t)(row_off + k) * N + n] : 0.f;
            }
        }
        __syncthreads();
        if (act) {
#pragma unroll
            for (int i = 0; i < 4; ++i) {
                int n = n0 + i * 8 + ty, k = k0 + tx;
                if (n < Npad && k < Kpad) {
                    int orow = (ilv >= 0) ? (ilv + 128 * (n >> 6) + (n & 63)) : n;
                    Wt[(size_t)orow * Kpad + k] = f2bf(tile[tx][i * 8 + ty]);
                }
            }
        }
    }
}

// ---------------------------------------------------------------------------
// ROUND 14: merged {Pcat 64x64 GEMM (256 blks) | topk (4096 blks, 4 rows ea)}
// — same-stream dispatches serialize, so topk previously ran fully BEFORE
// the Pcat GEMM despite independence. Merged, topk fills the wave slots the
// 256-block GEMM leaves idle. Pcat tiles keep EPI6 fused-ipre epilogue.
// ---------------------------------------------------------------------------
template <int KK>
__global__ __launch_bounds__(256) void pcat_topk_kernel(
    const short* __restrict__ A, const short* __restrict__ Wt,
    float* __restrict__ C, int ldc, const float* __restrict__ ib1,
    short* __restrict__ ipre_out,
    const float* __restrict__ logits, int* __restrict__ top0,
    int* __restrict__ top1, int* __restrict__ dis) {
    __shared__ __align__(16) short Asl[2][64][40];
    __shared__ __align__(16) short Bsl[2][64][40];
    int tid = threadIdx.x;

    if (blockIdx.x >= PCAT_BLK) {
        // topk: 4 rows per block, one per wave; no block barriers inside
        int b = (blockIdx.x - PCAT_BLK) * 4 + (tid >> 6);
        topk_body(b, tid & 63, logits, top0, top1, dis);
        return;
    }

    // Pcat 64x64 tile (flattened grid 32x8, chunked XCD swizzle)
    int wg = blockIdx.x;
    int swz = (wg & 7) * 32 + (wg >> 3);
    int bx = swz & 31, by = swz >> 5;
    int lane = tid & 63, wv = tid >> 6;
    int lm = lane & 15, q = lane >> 4;
    int row0 = by * 64;
    int col0 = bx * 64;

    float4v acc[4];
#pragma unroll
    for (int j = 0; j < 4; ++j) acc[j] = {0.f, 0.f, 0.f, 0.f};

    uint4 aReg, bReg;
    int ar = tid >> 2, ak = (tid & 3) * 8;   // 64 rows x 32 shorts: 1 uint4/thread

    auto loadG = [&](int k0) {
        aReg = *(const uint4*)&A[(size_t)(row0 + ar) * KK + k0 + ak];
        bReg = *(const uint4*)&Wt[(size_t)(col0 + ar) * KK + k0 + ak];
    };
    auto storeL = [&](int p) {
        *(uint4*)&Asl[p][ar][ak] = aReg;
        *(uint4*)&Bsl[p][ar][ak] = bReg;
    };

    int p = 0;
    loadG(0);
    storeL(0);
    for (int k0 = 0; k0 < KK; k0 += 32) {
        __syncthreads();
        bool more = (k0 + 32) < KK;
        if (more) loadG(k0 + 32);
        short8 af, bfr[4];
        af = *(const short8*)&Asl[p][wv * 16 + lm][q * 8];
#pragma unroll
        for (int nt = 0; nt < 4; ++nt)
            bfr[nt] = *(const short8*)&Bsl[p][nt * 16 + lm][q * 8];
#pragma unroll
        for (int nt = 0; nt < 4; ++nt)
            acc[nt] = __builtin_amdgcn_mfma_f32_16x16x32_bf16(
                af, bfr[nt], acc[nt], 0, 0, 0);
        if (more) { p ^= 1; storeL(p); }
    }

#pragma unroll
    for (int r = 0; r < 4; ++r) {
        int grow = row0 + wv * 16 + q * 4 + r;
#pragma unroll
        for (int nt = 0; nt < 4; ++nt) {
            int gcol = col0 + nt * 16 + lm;
            float v = acc[nt][r];
            C[(size_t)grow * ldc + gcol] = v;
            if (gcol >= 1536) {
                int j = gcol - 1536;
                float w = v + ib1[j];
                ipre_out[(size_t)grow * 512 + j] = f2bf(w > 0.f ? w : 0.f);
            }
        }
    }
}

// ---------------------------------------------------------------------------
// h1 = leaky(Pcat[top0,0:512] + Pcat[top1,512:1024] + b1) -> bf16
// ROUND 14: vectorized x8 (was scalar, Common-mistake #2). 4096 blocks,
// XCD-affine remap preserved: blk=(raw&7)*512+raw>>3 -> rows [2048k,2048k+2048)
// ---------------------------------------------------------------------------
__global__ __launch_bounds__(256) void h1_kernel(
    const float* __restrict__ Pcat, const float* __restrict__ b1,
    const int* __restrict__ top0, const int* __restrict__ top1,
    short* __restrict__ h1b) {
    int blk = (blockIdx.x & 7) * 512 + (blockIdx.x >> 3);   // 4096 blocks
    int idx = blk * 2048 + threadIdx.x * 8;
    int b = idx >> 9, j = idx & 511;
    const float* p0 = &Pcat[(size_t)top0[b] * 2048 + j];
    const float* p1 = &Pcat[(size_t)top1[b] * 2048 + 512 + j];
    float4 a0 = *(const float4*)p0;
    float4 a1 = *(const float4*)(p0 + 4);
    float4 c0 = *(const float4*)p1;
    float4 c1 = *(const float4*)(p1 + 4);
    float4 d0 = *(const float4*)&b1[j];
    float4 d1 = *(const float4*)&b1[j + 4];
    float t[8] = {a0.x + c0.x + d0.x, a0.y + c0.y + d0.y,
                  a0.z + c0.z + d0.z, a0.w + c0.w + d0.w,
                  a1.x + c1.x + d1.x, a1.y + c1.y + d1.y,
                  a1.z + c1.z + d1.z, a1.w + c1.w + d1.w};
    short8 o;
#pragma unroll
    for (int i = 0; i < 8; ++i) {
        float v = t[i];
        o[i] = f2bf(v > 0.f ? v : LEAK_ * v);
    }
    *(short8*)&h1b[idx] = o;
}

// ---------------------------------------------------------------------------
// core == ROUND 7 core (best measured config).
// 128x128, K=512, BK=64, 4 waves, double-buffered, COUNTED vmcnt (T4).
// ---------------------------------------------------------------------------
__device__ __forceinline__ const short8* frag_at(const short* buf, int row, int cb) {
    return (const short8*)&buf[row * 64 + ((cb ^ (row & 7)) * 8)];
}

__device__ __forceinline__ void gemm_core(
    const short* __restrict__ A, const short* __restrict__ Wt,
    int row0, int col0, int tid, short* As0, short* Bs0,
    short* As1, short* Bs1, float4v (&acc)[2][8]) {
    const int K = 512;
    int lane = tid & 63, wv = tid >> 6;
    int lm = lane & 15, q = lane >> 4;
    int rsub = lane >> 3;
    int kswz = ((lane & 7) ^ rsub) * 8;
    int ga = row0 + wv * 8 + rsub;
    int gb = col0 + wv * 8 + rsub;
#pragma unroll
    for (int i = 0; i < 2; ++i)
#pragma unroll
        for (int j = 0; j < 8; ++j) acc[i][j] = {0.f, 0.f, 0.f, 0.f};

    auto STAGE = [&](short* lA, short* lB, int k0) {
#pragma unroll
        for (int j = 0; j < 4; ++j) {
            gld16(&A[(size_t)(ga + 32 * j) * K + k0 + kswz],
                  lA + (wv * 8 + 32 * j) * 64);
            gld16(&Wt[(size_t)(gb + 32 * j) * K + k0 + kswz],
                  lB + (wv * 8 + 32 * j) * 64);
        }
    };

    STAGE(As0, Bs0, 0);
#pragma unroll
    for (int t = 0; t < 8; ++t) {
        short* cA = (t & 1) ? As1 : As0;
        short* cB = (t & 1) ? Bs1 : Bs0;
        short* nA = (t & 1) ? As0 : As1;
        short* nB = (t & 1) ? Bs0 : Bs1;
        if (t < 7) {
            STAGE(nA, nB, (t + 1) * 64);
            asm volatile("s_waitcnt vmcnt(8)" ::: "memory");
        } else {
            asm volatile("s_waitcnt vmcnt(0)" ::: "memory");
        }
        __builtin_amdgcn_s_barrier();
        __builtin_amdgcn_sched_barrier(0);
#pragma unroll
        for (int kk = 0; kk < 2; ++kk) {
            short8 af[2], bf[8];
#pragma unroll
            for (int mt = 0; mt < 2; ++mt)
                af[mt] = *frag_at(cA, wv * 32 + mt * 16 + lm, kk * 4 + q);
#pragma unroll
            for (int nt = 0; nt < 8; ++nt)
                bf[nt] = *frag_at(cB, nt * 16 + lm, kk * 4 + q);
#pragma unroll
            for (int mt = 0; mt < 2; ++mt)
#pragma unroll
                for (int nt = 0; nt < 8; ++nt)
                    acc[mt][nt] = __builtin_amdgcn_mfma_f32_16x16x32_bf16(
                        af[mt], bf[nt], acc[mt][nt], 0, 0, 0);
        }
        __builtin_amdgcn_s_barrier();
    }
}

// epilogues ----------------------------------------------------------------
template <int MODE>
__device__ __forceinline__ void epi_std(
    float4v (&acc)[2][8], int row0, int col0, int tid, void* C,
    const float* __restrict__ bias, const float* __restrict__ table,
    int tld, const int* __restrict__ rowsel) {
    int lane = tid & 63, wv = tid >> 6;
    int lm = lane & 15, q = lane >> 4;
#pragma unroll
    for (int mt = 0; mt < 2; ++mt)
#pragma unroll
        for (int r = 0; r < 4; ++r) {
            int grow = row0 + wv * 32 + mt * 16 + q * 4 + r;
            int trow = (MODE == 1) ? rowsel[grow] : 0;
#pragma unroll
            for (int nt = 0; nt < 8; ++nt) {
                int gcol = col0 + nt * 16 + lm;
                float v = acc[mt][nt][r] + bias[gcol];
                if (MODE == 1) {
                    v += table[(size_t)trow * tld + gcol];
                    v = v > 0.f ? v : LEAK_ * v;
                } else {
                    v = v > 0.f ? v : 0.f;
                }
                if (MODE == 4)
                    ((float*)C)[(size_t)grow * 512 + gcol] = v;
                else
                    ((short*)C)[(size_t)grow * 512 + gcol] = f2bf(v);
            }
        }
}

__device__ __forceinline__ void epi_recon(
    float4v (&acc)[2][8], int row0, int col0, int tid,
    const float* __restrict__ b4, const float* __restrict__ d_table,
    const int* __restrict__ top0, float* __restrict__ p_rec, int pidx,
    float* sred) {
    int lane = tid & 63, wv = tid >> 6;
    int lm = lane & 15, q = lane >> 4;
    float lsum = 0.f;
#pragma unroll
    for (int mt = 0; mt < 2; ++mt)
#pragma unroll
        for (int r = 0; r < 4; ++r) {
            int grow = row0 + wv * 32 + mt * 16 + q * 4 + r;
            int trow = top0[grow];
#pragma unroll
            for (int nt = 0; nt < 8; ++nt) {
                int gcol = col0 + nt * 16 + lm;
                if (gcol < F_) {
                    float v = tanhf(acc[mt][nt][r] + b4[gcol]);
                    float d = v - d_table[(size_t)trow * F_ + gcol];
                    lsum += d * d;
                }
            }
        }
    lsum = waveReduceSum(lsum);
    if (lane == 0) sred[wv] = lsum;
    __syncthreads();
    if (tid == 0) p_rec[pidx] = sred[0] + sred[1] + sred[2] + sred[3];
}

// ---------------------------------------------------------------------------
// mu|ls fused GEMM + reparam + KL partial. grid (8,128).
// ---------------------------------------------------------------------------
__global__ __launch_bounds__(256) void gemm_muls(
    const short* __restrict__ A, const short* __restrict__ Wt,
    short* __restrict__ Cz, short* __restrict__ Cz2,
    const float* __restrict__ bmu, const float* __restrict__ bls,
    const float* __restrict__ eps1, const float* __restrict__ eps2,
    float* __restrict__ p_kl) {
    __shared__ __align__(16) short As[2][128 * 64];
    __shared__ __align__(16) short Bs[2][128 * 64];
    __shared__ float sred[4];
    int tid = threadIdx.x;
    int bx, by;
    xcd_swizzle(bx, by);
    int row0 = by * 128, col0 = bx * 128;
    float4v acc[2][8];
    gemm_core(A, Wt, row0, col0, tid, As[0], Bs[0], As[1], Bs[1], acc);

    int lane = tid & 63, wv = tid >> 6;
    int lm = lane & 15, q = lane >> 4;
    float kl = 0.f;
#pragma unroll
    for (int mt = 0; mt < 2; ++mt) {
#pragma unroll
        for (int r = 0; r < 4; ++r) {
            int grow = row0 + wv * 32 + mt * 16 + q * 4 + r;
#pragma unroll
            for (int jj = 0; jj < 4; ++jj) {
                int j = (col0 >> 1) + jj * 16 + lm;
                float m = acc[mt][jj][r] + bmu[j];
                float lsv = acc[mt][jj + 4][r] + bls[j];
                float s = __expf(lsv);
                size_t ix = (size_t)grow * 512 + j;
                Cz[ix]  = f2bf(m + eps1[ix] * s);
                Cz2[ix] = f2bf(m + eps2[ix] * s);
                kl += -0.5f * (1.f + 2.f * lsv - m * m - s * s);
            }
        }
    }
    kl = waveReduceSum(kl);
    if (lane == 0) sred[wv] = kl;
    __syncthreads();
    if (tid == 0)
        p_kl[bx + gridDim.x * by] = sred[0] + sred[1] + sred[2] + sred[3];
}

// ---------------------------------------------------------------------------
// dual launch 1: {h3 (512) | t (512) | ipost (16)}; XCD-affine decode (r12)
// ---------------------------------------------------------------------------
__global__ __launch_bounds__(256) void dual12_kernel(
    const short* __restrict__ zA, const short* __restrict__ Wt3,
    short* __restrict__ h3out, const float* __restrict__ b3,
    const float* __restrict__ Ptab, const int* __restrict__ top1,
    const short* __restrict__ zpA, const short* __restrict__ Wtz1,
    short* __restrict__ tout, const float* __restrict__ zb1,
    const short* __restrict__ ipreA, const short* __restrict__ Wti2,
    float* __restrict__ ipostC, const float* __restrict__ ib2,
    int jobSel) {
    __shared__ __align__(16) short As[2][128 * 64];
    __shared__ __align__(16) short Bs[2][128 * 64];
    int tid = threadIdx.x;
    int k = blockIdx.x & 7, m = blockIdx.x >> 3;
    int job, bx, by;
    if (jobSel >= 0) {
        job = jobSel;
        if (job == 2) { int idx = k * 2 + m; bx = idx & 3; by = idx >> 2; }
        else { bx = m & 3; by = 16 * k + (m >> 2); }
    } else {
        if (m < 64)       { job = 0; bx = m & 3; by = 16 * k + (m >> 2); }
        else if (m < 128) { int mm = m - 64; job = 1; bx = mm & 3; by = 16 * k + (mm >> 2); }
        else              { int mm = m - 128; job = 2; int idx = k * 2 + mm; bx = idx & 3; by = idx >> 2; }
    }
    int row0 = by * 128, col0 = bx * 128;
    float4v acc[2][8];
    if (job == 0) {
        gemm_core(zA, Wt3, row0, col0, tid, As[0], Bs[0], As[1], Bs[1], acc);
        epi_std<1>(acc, row0, col0, tid, h3out, b3, Ptab, 2048, top1);
    } else if (job == 1) {
        gemm_core(zpA, Wtz1, row0, col0, tid, As[0], Bs[0], As[1], Bs[1], acc);
        epi_std<2>(acc, row0, col0, tid, tout, zb1, nullptr, 0, nullptr);
    } else {
        gemm_core(ipreA, Wti2, row0, col0, tid, As[0], Bs[0], As[1], Bs[1], acc);
        epi_std<4>(acc, row0, col0, tid, ipostC, ib2, nullptr, 0, nullptr);
    }
}

// ---------------------------------------------------------------------------
// dual launch 2: {z_p (512) | recon (384)}; XCD-affine decode (r12)
// ---------------------------------------------------------------------------
__global__ __launch_bounds__(256) void dual34_kernel(
    const short* __restrict__ tA, const short* __restrict__ Wtz2,
    float* __restrict__ zpout, const float* __restrict__ zb2,
    const short* __restrict__ h3A, const short* __restrict__ Wt4,
    const float* __restrict__ b4, const float* __restrict__ d_table,
    const int* __restrict__ top0, float* __restrict__ p_rec, int jobSel) {
    __shared__ __align__(16) short As[2][128 * 64];
    __shared__ __align__(16) short Bs[2][128 * 64];
    __shared__ float sred[4];
    int tid = threadIdx.x;
    int k = blockIdx.x & 7, m = blockIdx.x >> 3;
    int job, bx, by;
    if (jobSel >= 0) {
        job = jobSel;
        if (job == 0) { bx = m & 3; by = 16 * k + (m >> 2); }
        else          { bx = m % 3; by = 16 * k + m / 3; }
    } else {
        if (m < 64) { job = 0; bx = m & 3; by = 16 * k + (m >> 2); }
        else        { int mm = m - 64; job = 1; bx = mm % 3; by = 16 * k + mm / 3; }
    }
    float4v acc[2][8];
    if (job == 0) {
        int row0 = by * 128, col0 = bx * 128;
        gemm_core(tA, Wtz2, row0, col0, tid, As[0], Bs[0], As[1], Bs[1], acc);
        epi_std<4>(acc, row0, col0, tid, zpout, zb2, nullptr, 0, nullptr);
    } else {
        int row0 = by * 128, col0 = bx * 128;
        gemm_core(h3A, Wt4, row0, col0, tid, As[0], Bs[0], As[1], Bs[1], acc);
        epi_recon(acc, row0, col0, tid, b4, d_table, top0, p_rec,
                  bx + 3 * by, sred);
    }
}

// ---------------------------------------------------------------------------
// contrastive loss: one wave per row; XCD-affine block remap (r12)
// ---------------------------------------------------------------------------
__global__ __launch_bounds__(256) void csl_kernel(
    const float* __restrict__ zp, const float* __restrict__ ipost,
    const int* __restrict__ top0, const int* __restrict__ dis,
    float* __restrict__ partial_csl) {
    __shared__ float sred[4];
    int blk = (blockIdx.x & 7) * 512 + (blockIdx.x >> 3);   // 4096 blocks
    int w = threadIdx.x >> 6, lane = threadIdx.x & 63;
    int b = blk * 4 + w;
    const float* zr = zp + (size_t)b * 512;
    float z[8];
#pragma unroll
    for (int i = 0; i < 8; ++i) z[i] = zr[i * 64 + lane];
    int cand[16];
    cand[0] = top0[b];
#pragma unroll
    for (int n = 0; n < DISK_; ++n) cand[n + 1] = dis[b * DISK_ + n];
    float s[16];
#pragma unroll
    for (int c = 0; c < 16; ++c) {
        const float* ip = ipost + (size_t)cand[c] * 512;
        float a = 0.f;
#pragma unroll
        for (int i = 0; i < 8; ++i) a += z[i] * ip[i * 64 + lane];
        s[c] = a;
    }
#pragma unroll
    for (int off = 32; off; off >>= 1) {
        float o[16];
#pragma unroll
        for (int c = 0; c < 16; ++c) o[c] = __shfl_xor(s[c], off);
#pragma unroll
        for (int c = 0; c < 16; ++c) s[c] += o[c];
    }
    if (lane == 0) {
        float m = s[0];
#pragma unroll
        for (int c = 1; c < 16; ++c) m = fmaxf(m, s[c]);
        float se = 0.f;
#pragma unroll
        for (int c = 0; c < 16; ++c) se += __expf((s[c] - m) / TEMP_);
        sred[w] = -((s[0] - m) / TEMP_ - __logf(se));
    }
    __syncthreads();
    if (threadIdx.x == 0)
        partial_csl[blk] = sred[0] + sred[1] + sred[2] + sred[3];
}

// ---------------------------------------------------------------------------
// finalize: out[0] = kl + recon; out[1] = csl; out[2..513] = 0 (z_rel row 0)
// ---------------------------------------------------------------------------
__global__ __launch_bounds__(256) void finalize_kernel(
    const float* __restrict__ pkl, const float* __restrict__ prec,
    const float* __restrict__ pcsl, float* __restrict__ out) {
    __shared__ float red[4][2];
    int tid = threadIdx.x;
    out[2 + tid] = 0.f;
    out[2 + 256 + tid] = 0.f;
    float a0 = 0.f, a1 = 0.f;
    for (int i = tid; i < NKL_BLK; i += 256) a0 += pkl[i];
    for (int i = tid; i < NREC_BLK; i += 256) a0 += prec[i];
    for (int i = tid; i < NCSL_BLK; i += 256) a1 += pcsl[i];
    a0 = waveReduceSum(a0);
    a1 = waveReduceSum(a1);
    int lane = tid & 63, w = tid >> 6;
    if (lane == 0) { red[w][0] = a0; red[w][1] = a1; }
    __syncthreads();
    if (tid == 0) out[0] = red[0][0] + red[1][0] + red[2][0] + red[3][0];
    if (tid == 1) out[1] = red[0][1] + red[1][1] + red[2][1] + red[3][1];
}

// ---------------------------------------------------------------------------
extern "C" void kernel_launch(void* const* d_in, const int* in_sizes, int n_in,
                              void* d_out, int out_size, void* d_ws, size_t ws_size,
                              hipStream_t stream) {
    const float* logits  = (const float*)d_in[0];
    const int*   rels    = (const int*)d_in[1];
    const float* rel_dict= (const float*)d_in[2];
    const float* eps1    = (const float*)d_in[3];
    const float* eps2    = (const float*)d_in[4];
    const float* W1  = (const float*)d_in[5];
    const float* b1  = (const float*)d_in[6];
    const float* Wmu = (const float*)d_in[7];
    const float* bmu = (const float*)d_in[8];
    const float* Wls = (const float*)d_in[9];
    const float* bls = (const float*)d_in[10];
    const float* W3  = (const float*)d_in[11];
    const float* b3  = (const float*)d_in[12];
    const float* W4  = (const float*)d_in[13];
    const float* b4  = (const float*)d_in[14];
    const float* iW1 = (const float*)d_in[15];
    const float* ib1 = (const float*)d_in[16];
    const float* iW2 = (const float*)d_in[17];
    const float* ib2 = (const float*)d_in[18];
    const float* zW1 = (const float*)d_in[19];
    const float* zb1 = (const float*)d_in[20];
    const float* zW2 = (const float*)d_in[21];
    const float* zb2 = (const float*)d_in[22];
    float* out = (float*)d_out;

    char* wsp = (char*)d_ws;
    size_t off = 0;
    auto alloc = [&](size_t bytes) { void* p = wsp + off; off += (bytes + 255) & ~(size_t)255; return p; };
    int*   top0    = (int*)alloc(B_ * 4);
    int*   top1    = (int*)alloc(B_ * 4);
    int*   dis     = (int*)alloc(B_ * DISK_ * 4);
    float* d_table = (float*)alloc((size_t)R_ * F_ * 4);
    short* dt      = (short*)alloc((size_t)R_ * FP_ * 2);
    short* Wcat_t  = (short*)alloc((size_t)2048 * FP_ * 2);
    float* Pcat    = (float*)alloc((size_t)R_ * 2048 * 4);
    short* ipre    = (short*)alloc((size_t)R_ * H_ * 2);
    float* ipost   = (float*)alloc((size_t)R_ * H_ * 4);
    short* Wt_muls = (short*)alloc((size_t)1024 * 512 * 2);
    short* Wt_3    = (short*)alloc((size_t)512 * 512 * 2);
    short* Wt_z1   = (short*)alloc((size_t)512 * 512 * 2);
    short* Wt_z2   = (short*)alloc((size_t)512 * 512 * 2);
    short* Wt_4    = (short*)alloc((size_t)384 * 512 * 2);  // padded to 384 rows
    short* Wt_i2   = (short*)alloc((size_t)512 * 512 * 2);
    short* bfA     = (short*)alloc((size_t)B_ * H_ * 2);   // h1 -> h3
    short* bfB     = (short*)alloc((size_t)B_ * H_ * 2);   // z
    short* bfC     = (short*)alloc((size_t)B_ * H_ * 2);   // z_
    float* p_csl   = (float*)alloc(NCSL_BLK * 4);
    float* p_kl    = (float*)alloc(NKL_BLK * 4);
    float* p_rec   = (float*)alloc(NREC_BLK * 4);
    // t buffer: only if workspace allows (enables the merged dual launches)
    size_t bfD_bytes = (size_t)B_ * H_ * 2;
    bool merged = (off + bfD_bytes + 256) <= ws_size;
    short* bfD = merged ? (short*)alloc(bfD_bytes) : bfB;

    TransArgs ta;
    auto set = [&](int i, const float* W, short* Wt, int ro, int K, int Kp, int N, int Np, int ilv) {
        ta.W[i] = W; ta.Wt[i] = Wt; ta.row_off[i] = ro; ta.K[i] = K;
        ta.Kpad[i] = Kp; ta.N[i] = N; ta.Npad[i] = Np; ta.ilv[i] = ilv;
    };
    set(0, Wmu, Wt_muls, 0, 512, 512, 512, 512, 0);    // rows 128c+[0,64)
    set(1, Wls, Wt_muls, 0, 512, 512, 512, 512, 64);   // rows 128c+[64,128)
    set(2, W3,  Wt_3,  0, 512, 512, 512, 512, -1);
    set(3, zW1, Wt_z1, 0, 512, 512, 512, 512, -1);
    set(4, zW2, Wt_z2, 0, 512, 512, 512, 512, -1);
    set(5, W4,  Wt_4,  0, 512, 512, 300, 384, -1);     // zero-padded cols 300..384
    set(6, W1,  Wcat_t,              0,  F_, FP_, 512, 512, -1);   // P1
    set(7, W1,  Wcat_t + 512 * FP_,  F_, F_, FP_, 512, 512, -1);   // P2
    set(8, W3,  Wcat_t + 1024 * FP_, L_, F_, FP_, 512, 512, -1);   // P3
    set(9, iW1, Wcat_t + 1536 * FP_, 0,  F_, FP_, 512, 512, -1);   // ipre
    set(10, iW2, Wt_i2, 0, 512, 512, 512, 512, -1);

    // front-end: gather | transpose (topk moved into the Pcat dispatch)
    front_kernel<<<FRONT_GATHER_BLK + FRONT_TRANS_BLK, 320, 0, stream>>>(
        rels, rel_dict, d_table, dt, ta);

    // merged {Pcat GEMM (fused ipre) | topk} — independent jobs overlap
    pcat_topk_kernel<FP_><<<PCAT_BLK + TOPK_BLK, 256, 0, stream>>>(
        dt, Wcat_t, Pcat, 2048, ib1, ipre, logits, top0, top1, dis);

    h1_kernel<<<4096, 256, 0, stream>>>(Pcat, b1, top0, top1, bfA);

    // fused mu|ls -> z (bfB), z_ (bfC), kl partials
    gemm_muls<<<dim3(8, 128), 256, 0, stream>>>(
        bfA, Wt_muls, bfB, bfC, bmu, bls, eps1, eps2, p_kl);

    if (merged) {
        dual12_kernel<<<1040, 256, 0, stream>>>(
            bfB, Wt_3, bfA, b3, Pcat + 1024, top1,
            bfC, Wt_z1, bfD, zb1,
            ipre, Wt_i2, ipost, ib2, -1);
        dual34_kernel<<<896, 256, 0, stream>>>(
            bfD, Wt_z2, out + 2 + L_, zb2,
            bfA, Wt_4, b4, d_table, top0, p_rec, -1);
    } else {
        dual12_kernel<<<512, 256, 0, stream>>>(
            bfB, Wt_3, bfA, b3, Pcat + 1024, top1,
            bfC, Wt_z1, bfD, zb1, ipre, Wt_i2, ipost, ib2, 0);
        dual12_kernel<<<512, 256, 0, stream>>>(
            bfB, Wt_3, bfA, b3, Pcat + 1024, top1,
            bfC, Wt_z1, bfD, zb1, ipre, Wt_i2, ipost, ib2, 1);
        dual12_kernel<<<16, 256, 0, stream>>>(
            bfB, Wt_3, bfA, b3, Pcat + 1024, top1,
            bfC, Wt_z1, bfD, zb1, ipre, Wt_i2, ipost, ib2, 2);
        dual34_kernel<<<512, 256, 0, stream>>>(
            bfD, Wt_z2, out + 2 + L_, zb2,
            bfA, Wt_4, b4, d_table, top0, p_rec, 0);
        dual34_kernel<<<384, 256, 0, stream>>>(
            bfD, Wt_z2, out + 2 + L_, zb2,
            bfA, Wt_4, b4, d_table, top0, p_rec, 1);
    }

    csl_kernel<<<NCSL_BLK, 256, 0, stream>>>(out + 2 + L_, ipost, top0, dis, p_csl);
    finalize_kernel<<<1, 256, 0, stream>>>(p_kl, p_rec, p_csl, out);
}